// Round 6
// baseline (341.196 us; speedup 1.0000x reference)
//
#include <hip/hip_runtime.h>

#define N_NODES 50000
#define N_EDGES 800000
#define EPS 1e-5f

typedef __attribute__((ext_vector_type(8))) short bf16x8;
typedef __attribute__((ext_vector_type(4))) float f32x4;
typedef __attribute__((ext_vector_type(4))) unsigned short us4;

__device__ __forceinline__ unsigned short f2b(float f) {
    union { float f; unsigned int u; } v; v.f = f;
    unsigned int r = v.u + 0x7fffu + ((v.u >> 16) & 1u);
    return (unsigned short)(r >> 16);
}
__device__ __forceinline__ float b2f(unsigned short b) {
    union { unsigned int u; float f; } v; v.u = ((unsigned int)b) << 16;
    return v.f;
}

// red layout per layer: 64 buckets * 16 floats (one 64B line per bucket).
#define RED_BUCKETS 64
#define RED_FLOATS_PER_LAYER (RED_BUCKETS * 16)

// ---------------- CSR build ----------------

__global__ void init_kernel(int* __restrict__ deg, int* __restrict__ fill,
                            float* __restrict__ red, int n) {
    int i = blockIdx.x * blockDim.x + threadIdx.x;
    if (i < n) { deg[i] = 0; fill[i] = 0; }
    if (i < 3 * RED_FLOATS_PER_LAYER) red[i] = 0.f;
}

__global__ void count_kernel(const int* __restrict__ dst, int* __restrict__ deg, int e) {
    for (int i = blockIdx.x * blockDim.x + threadIdx.x; i < e; i += gridDim.x * blockDim.x)
        atomicAdd(&deg[dst[i]], 1);
}

// scan1 also emits dinv (deg is final here)
__global__ void scan1_kernel(const int* __restrict__ deg, float* __restrict__ dinv,
                             int* __restrict__ bsum, int n) {
    int i = blockIdx.x * 256 + threadIdx.x;
    int v = (i < n) ? deg[i] : 0;
    if (i < n) dinv[i] = rsqrtf((float)(v + 1));  // +1 self-loop
    int t = v;
    #pragma unroll
    for (int off = 1; off < 64; off <<= 1) t += __shfl_xor(t, off);
    __shared__ int wsum[4];
    int wid = threadIdx.x >> 6, lane = threadIdx.x & 63;
    if (lane == 0) wsum[wid] = t;
    __syncthreads();
    if (threadIdx.x == 0) bsum[blockIdx.x] = wsum[0] + wsum[1] + wsum[2] + wsum[3];
}

__global__ void scan2_kernel(const int* __restrict__ bsum, int* __restrict__ bpre, int nb) {
    __shared__ int sm[256];
    int t = threadIdx.x;
    sm[t] = (t < nb) ? bsum[t] : 0;
    __syncthreads();
    #pragma unroll
    for (int d = 1; d < 256; d <<= 1) {
        int x = (t >= d) ? sm[t - d] : 0;
        __syncthreads();
        sm[t] += x;
        __syncthreads();
    }
    bpre[t] = (t > 0) ? sm[t - 1] : 0;  // exclusive
}

__global__ void scan3_kernel(const int* __restrict__ deg, const int* __restrict__ bpre,
                             int* __restrict__ off, int n) {
    __shared__ int sm[256];
    int t = threadIdx.x;
    int i = blockIdx.x * 256 + t;
    int v = (i < n) ? deg[i] : 0;
    sm[t] = v;
    __syncthreads();
    #pragma unroll
    for (int d = 1; d < 256; d <<= 1) {
        int x = (t >= d) ? sm[t - d] : 0;
        __syncthreads();
        sm[t] += x;
        __syncthreads();
    }
    if (i < n) off[i + 1] = sm[t] + bpre[blockIdx.x];
    if (i == 0) off[0] = 0;
}

// pack (src, weight) per edge slot: one 8B load at gather time
__global__ void scatter_kernel(const int* __restrict__ src, const int* __restrict__ dst,
                               const int* __restrict__ coff, int* __restrict__ fill,
                               const float* __restrict__ dinv,
                               int2* __restrict__ epack, int e) {
    for (int i = blockIdx.x * blockDim.x + threadIdx.x; i < e; i += gridDim.x * blockDim.x) {
        int d = dst[i];
        int s = src[i];
        int pos = coff[d] + atomicAdd(&fill[d], 1);
        epack[pos] = make_int2(s, __float_as_int(dinv[s] * dinv[d]));
    }
}

// ---------------- fused f32 -> bf16 converts (x0, W0, W1, W2 in one launch) ----------------

#define CV_NX (N_NODES * 128 / 4)
#define CV_N0 (256 * 128 / 4)
#define CV_N1 (256 * 256 / 4)
#define CV_N2 (128 * 256 / 4)

__global__ void convert_all(const float* __restrict__ x0, const float* __restrict__ W0,
                            const float* __restrict__ W1, const float* __restrict__ W2,
                            unsigned short* __restrict__ xb, unsigned short* __restrict__ wb0,
                            unsigned short* __restrict__ wb1, unsigned short* __restrict__ wb2) {
    int i = blockIdx.x * 256 + threadIdx.x;
    const float* s;
    unsigned short* d;
    int j = i;
    if (j < CV_NX) { s = x0; d = xb; }
    else if ((j -= CV_NX) < CV_N0) { s = W0; d = wb0; }
    else if ((j -= CV_N0) < CV_N1) { s = W1; d = wb1; }
    else if ((j -= CV_N1) < CV_N2) { s = W2; d = wb2; }
    else return;
    float4 v = reinterpret_cast<const float4*>(s)[j];
    us4 o;
    o[0] = f2b(v.x); o[1] = f2b(v.y); o[2] = f2b(v.z); o[3] = f2b(v.w);
    reinterpret_cast<us4*>(d)[j] = o;
}

// ---------------- fused GEMM ----------------
// H[m][n] = sum_k T(X[m][k]) * W[n][k] (+bias)
// BM=64, BN=fout (128/256), BK=32; 4 waves split N.
// TRANSFORM: X is bf16 y_prev; apply graph-LN (stats from red buckets) + PReLU.
// FUSE_RED: accumulate sum/sumsq of outputs into redout buckets.

template<int BN, bool TRANSFORM, bool ADD_BIAS, bool FUSE_RED>
__global__ __launch_bounds__(256) void gemm_fused(
    const unsigned short* __restrict__ Xin, const unsigned short* __restrict__ Wb,
    const float* __restrict__ bias, const float* __restrict__ redin,
    const float* __restrict__ gw, const float* __restrict__ bw,
    const float* __restrict__ asl, float* __restrict__ redout,
    unsigned short* __restrict__ Hout, int M, int K, float inv_count) {
    constexpr int FR_N = BN / 64;
    __shared__ unsigned short xs[64 * 32];
    __shared__ unsigned short wsm[BN * 32];
    int m0 = blockIdx.x * 64;
    int tid = threadIdx.x;
    int wid = tid >> 6, lane = tid & 63;
    int l16 = lane & 15, kg = lane >> 4;
    int srow = tid >> 2, sblk = tid & 3;

    float mu = 0.f, rstd = 0.f, alpha = 0.f;
    if (TRANSFORM) {
        float s = redin[lane * 16], s2 = redin[lane * 16 + 1];
        #pragma unroll
        for (int off = 1; off < 64; off <<= 1) { s += __shfl_xor(s, off); s2 += __shfl_xor(s2, off); }
        mu = s * inv_count;
        rstd = rsqrtf(s2 * inv_count - mu * mu + EPS);
        alpha = asl[0];
    }

    f32x4 acc[4][FR_N] = {};
    for (int k0 = 0; k0 < K; k0 += 32) {
        int gm = m0 + srow;
        bf16x8 xv = {};
        if (gm < M) {
            bf16x8 u = *reinterpret_cast<const bf16x8*>(Xin + (size_t)gm * K + k0 + sblk * 8);
            if (TRANSFORM) {
                #pragma unroll
                for (int i = 0; i < 8; ++i) {
                    int f = k0 + sblk * 8 + i;
                    float v = (b2f((unsigned short)u[i]) - mu) * rstd * gw[f] + bw[f];
                    v = v >= 0.f ? v : alpha * v;
                    xv[i] = (short)f2b(v);
                }
            } else {
                xv = u;
            }
        }
        *reinterpret_cast<bf16x8*>(xs + srow * 32 + ((sblk ^ (srow & 3)) * 8)) = xv;
        #pragma unroll
        for (int i = 0; i < BN / 64; ++i) {
            int idx = tid + i * 256;
            int wrow = idx >> 2, wblk = idx & 3;
            bf16x8 wv = *reinterpret_cast<const bf16x8*>(Wb + (size_t)wrow * K + k0 + wblk * 8);
            *reinterpret_cast<bf16x8*>(wsm + wrow * 32 + ((wblk ^ (wrow & 3)) * 8)) = wv;
        }
        __syncthreads();
        bf16x8 a[4], b[FR_N];
        #pragma unroll
        for (int f = 0; f < 4; ++f) {
            int ar = f * 16 + l16;
            a[f] = *reinterpret_cast<const bf16x8*>(xs + ar * 32 + ((kg ^ (ar & 3)) * 8));
        }
        #pragma unroll
        for (int f = 0; f < FR_N; ++f) {
            int br = wid * (FR_N * 16) + f * 16 + l16;
            b[f] = *reinterpret_cast<const bf16x8*>(wsm + br * 32 + ((kg ^ (br & 3)) * 8));
        }
        #pragma unroll
        for (int i = 0; i < 4; ++i)
            #pragma unroll
            for (int j = 0; j < FR_N; ++j)
                acc[i][j] = __builtin_amdgcn_mfma_f32_16x16x32_bf16(a[i], b[j], acc[i][j], 0, 0, 0);
        __syncthreads();
    }

    float s = 0.f, s2 = 0.f;
    #pragma unroll
    for (int i = 0; i < 4; ++i) {
        #pragma unroll
        for (int j = 0; j < FR_N; ++j) {
            int col = wid * (FR_N * 16) + j * 16 + l16;
            float bv = ADD_BIAS ? bias[col] : 0.f;
            #pragma unroll
            for (int r = 0; r < 4; ++r) {
                int row = m0 + i * 16 + kg * 4 + r;
                if (row < M) {
                    float v = acc[i][j][r] + bv;
                    if (FUSE_RED) { s += v; s2 += v * v; }
                    Hout[(size_t)row * BN + col] = f2b(v);
                }
            }
        }
    }
    if (FUSE_RED) {
        #pragma unroll
        for (int off = 1; off < 64; off <<= 1) { s += __shfl_xor(s, off); s2 += __shfl_xor(s2, off); }
        if (lane == 0) {
            int bkt = (blockIdx.x & (RED_BUCKETS - 1)) * 16;
            atomicAdd(&redout[bkt], s);
            atomicAdd(&redout[bkt + 1], s2);
        }
    }
}

// ---------------- aggregation: wave per node, depth-2 software-pipelined gather ----------------
// Y[n] = (bias) + dinv[n]^2 * H[n] + sum_e w_e * H[src_e], f32 accumulate over bf16 rows.

template<int COLS, bool ADD_BIAS, bool FUSE_RED>
__global__ void aggregate2(const unsigned short* __restrict__ Hb,
                           const int* __restrict__ coff, const int2* __restrict__ epack,
                           const float* __restrict__ dinv,
                           const float* __restrict__ bias, unsigned short* __restrict__ Y,
                           float* __restrict__ red) {
    constexpr int RL = COLS / 8;   // lanes per row (16B each): 16 or 32
    constexpr int NG = 64 / RL;    // neighbor groups per wave: 4 or 2
    int node = blockIdx.x * 4 + (threadIdx.x >> 6);
    int lane = threadIdx.x & 63;
    int g = lane / RL;
    int rl = lane % RL;
    float di = dinv[node];
    int s0 = coff[node], s1 = coff[node + 1];
    float acc[8] = {};

    // depth-2 pipeline: row load for neighbor k+NG is in flight while k is consumed
    int k = s0 - 1 + g;
    int2 ec;
    bf16x8 vc;
    bool have = (k < s1);
    if (have) {
        if (k < s0) ec = make_int2(node, __float_as_int(di * di));
        else ec = epack[k];
        vc = *reinterpret_cast<const bf16x8*>(Hb + (size_t)ec.x * COLS + rl * 8);
    }
    while (have) {
        int k2 = k + NG;
        bool have2 = (k2 < s1);
        int2 en;
        bf16x8 vn;
        if (have2) {
            en = epack[k2];   // k2 >= s0 always
            vn = *reinterpret_cast<const bf16x8*>(Hb + (size_t)en.x * COLS + rl * 8);
        }
        float w = __int_as_float(ec.y);
        #pragma unroll
        for (int i = 0; i < 8; ++i) acc[i] += w * b2f((unsigned short)vc[i]);
        k = k2; ec = en; vc = vn; have = have2;
    }

    // combine groups
    #pragma unroll
    for (int off = RL; off < 64; off <<= 1) {
        #pragma unroll
        for (int i = 0; i < 8; ++i) acc[i] += __shfl_xor(acc[i], off);
    }
    if (ADD_BIAS) {
        #pragma unroll
        for (int i = 0; i < 8; ++i) acc[i] += bias[rl * 8 + i];
    }
    if (FUSE_RED) {
        float s = 0.f, s2 = 0.f;
        if (g == 0) {
            #pragma unroll
            for (int i = 0; i < 8; ++i) { s += acc[i]; s2 += acc[i] * acc[i]; }
        }
        #pragma unroll
        for (int off = 1; off < 64; off <<= 1) { s += __shfl_xor(s, off); s2 += __shfl_xor(s2, off); }
        if (lane == 0) {
            int bkt = (blockIdx.x & (RED_BUCKETS - 1)) * 16;
            atomicAdd(&red[bkt], s);
            atomicAdd(&red[bkt + 1], s2);
        }
    }
    if (g == 0) {
        bf16x8 o;
        #pragma unroll
        for (int i = 0; i < 8; ++i) o[i] = (short)f2b(acc[i]);
        // nontemporal: don't evict gather-hot H lines with the output stream
        __builtin_nontemporal_store(o, reinterpret_cast<bf16x8*>(Y + (size_t)node * COLS + rl * 8));
    }
}

// ---------------- final LayerNorm + PReLU (bf16 in, f32 out) ----------------

__global__ void norm_final(const unsigned short* __restrict__ Yb, const float* __restrict__ red,
                           const float* __restrict__ g, const float* __restrict__ be,
                           const float* __restrict__ a, float* __restrict__ X,
                           int fmask8, int n8, float inv_count) {
    int lane = threadIdx.x & 63;
    float s = red[lane * 16], s2 = red[lane * 16 + 1];
    #pragma unroll
    for (int off = 1; off < 64; off <<= 1) { s += __shfl_xor(s, off); s2 += __shfl_xor(s2, off); }
    float mu = s * inv_count;
    float rstd = rsqrtf(s2 * inv_count - mu * mu + EPS);
    float alpha = a[0];
    for (int i = blockIdx.x * blockDim.x + threadIdx.x; i < n8; i += gridDim.x * blockDim.x) {
        bf16x8 v = reinterpret_cast<const bf16x8*>(Yb)[i];
        int fb = (i & fmask8) * 8;
        float o[8];
        #pragma unroll
        for (int j = 0; j < 8; ++j) {
            float t = (b2f((unsigned short)v[j]) - mu) * rstd * g[fb + j] + be[fb + j];
            o[j] = t >= 0.f ? t : alpha * t;
        }
        float* xp = X + (size_t)i * 8;
        *reinterpret_cast<float4*>(xp) = make_float4(o[0], o[1], o[2], o[3]);
        *reinterpret_cast<float4*>(xp + 4) = make_float4(o[4], o[5], o[6], o[7]);
    }
}

// ---------------- launch ----------------

extern "C" void kernel_launch(void* const* d_in, const int* in_sizes, int n_in,
                              void* d_out, int out_size, void* d_ws, size_t ws_size,
                              hipStream_t stream) {
    const float* x0 = (const float*)d_in[0];
    const int* ei = (const int*)d_in[1];
    const float* W[3] = {(const float*)d_in[2], (const float*)d_in[7], (const float*)d_in[12]};
    const float* bb[3] = {(const float*)d_in[3], (const float*)d_in[8], (const float*)d_in[13]};
    const float* gg[3] = {(const float*)d_in[4], (const float*)d_in[9], (const float*)d_in[14]};
    const float* be[3] = {(const float*)d_in[5], (const float*)d_in[10], (const float*)d_in[15]};
    const float* aa[3] = {(const float*)d_in[6], (const float*)d_in[11], (const float*)d_in[16]};

    char* ws = (char*)d_ws;
    size_t o = 0;
    auto alloc = [&](size_t bytes) {
        void* p = ws + o;
        o = (o + bytes + 255) & ~(size_t)255;
        return p;
    };
    int* deg = (int*)alloc(N_NODES * 4);
    int* fill = (int*)alloc(N_NODES * 4);
    int* coff = (int*)alloc((N_NODES + 1) * 4);
    int2* epack = (int2*)alloc((size_t)N_EDGES * 8);
    float* dinv = (float*)alloc(N_NODES * 4);
    int* bsum = (int*)alloc(256 * 4);
    int* bpre = (int*)alloc(256 * 4);
    float* red = (float*)alloc(3 * RED_FLOATS_PER_LAYER * 4);
    unsigned short* Wb0 = (unsigned short*)alloc(256 * 128 * 2);
    unsigned short* Wb1 = (unsigned short*)alloc(256 * 256 * 2);
    unsigned short* Wb2 = (unsigned short*)alloc(128 * 256 * 2);
    unsigned short* xb = (unsigned short*)alloc((size_t)N_NODES * 128 * 2);
    unsigned short* hb = (unsigned short*)alloc((size_t)N_NODES * 256 * 2);
    unsigned short* yb = (unsigned short*)alloc((size_t)N_NODES * 256 * 2);

    const int* e_src = ei;
    const int* e_dst = ei + N_EDGES;
    int nb = (N_NODES + 255) / 256;  // 196

    // CSR build
    init_kernel<<<(N_NODES + 255) / 256, 256, 0, stream>>>(deg, fill, red, N_NODES);
    count_kernel<<<2048, 256, 0, stream>>>(e_dst, deg, N_EDGES);
    scan1_kernel<<<nb, 256, 0, stream>>>(deg, dinv, bsum, N_NODES);
    scan2_kernel<<<1, 256, 0, stream>>>(bsum, bpre, nb);
    scan3_kernel<<<nb, 256, 0, stream>>>(deg, bpre, coff, N_NODES);
    scatter_kernel<<<2048, 256, 0, stream>>>(e_src, e_dst, coff, fill, dinv, epack, N_EDGES);

    // converts (x + 3 weights) in one launch
    int cvtot = CV_NX + CV_N0 + CV_N1 + CV_N2;
    convert_all<<<(cvtot + 255) / 256, 256, 0, stream>>>(x0, W[0], W[1], W[2], xb, Wb0, Wb1, Wb2);

    int gm = (N_NODES + 63) / 64;  // 782

    // ---- Layer 0: aggregate x (128 cols) -> GEMM(+bias,+reduce) -> yb bf16 ----
    aggregate2<128, false, false><<<12500, 256, 0, stream>>>(xb, coff, epack, dinv,
                                                             nullptr, hb, nullptr);
    gemm_fused<256, false, true, true><<<gm, 256, 0, stream>>>(
        hb, Wb0, bb[0], nullptr, nullptr, nullptr, nullptr, red + 0, yb, N_NODES, 128,
        1.0f / (N_NODES * 256.0f));

    // ---- Layer 1: GEMM(transform LN0+PReLU) -> hb; aggregate(+bias,+red) -> yb ----
    gemm_fused<256, true, false, false><<<gm, 256, 0, stream>>>(
        yb, Wb1, nullptr, red + 0, gg[0], be[0], aa[0], nullptr, hb, N_NODES, 256,
        1.0f / (N_NODES * 256.0f));
    aggregate2<256, true, true><<<12500, 256, 0, stream>>>(
        hb, coff, epack, dinv, bb[1], yb, red + RED_FLOATS_PER_LAYER);

    // ---- Layer 2: GEMM(transform LN1+PReLU) -> hb (128); aggregate(+bias,+red) -> yb ----
    gemm_fused<128, true, false, false><<<gm, 256, 0, stream>>>(
        yb, Wb2, nullptr, red + RED_FLOATS_PER_LAYER, gg[1], be[1], aa[1], nullptr, hb,
        N_NODES, 256, 1.0f / (N_NODES * 256.0f));
    aggregate2<128, true, true><<<12500, 256, 0, stream>>>(
        hb, coff, epack, dinv, bb[2], yb, red + 2 * RED_FLOATS_PER_LAYER);

    // ---- final LN + PReLU -> d_out f32 ----
    norm_final<<<2048, 256, 0, stream>>>(yb, red + 2 * RED_FLOATS_PER_LAYER, gg[2], be[2], aa[2],
                                         (float*)d_out, 15, N_NODES * 128 / 8,
                                         1.0f / (N_NODES * 128.0f));
}

// Round 7
// 341.134 us; speedup vs baseline: 1.0002x; 1.0002x over previous
//
#include <hip/hip_runtime.h>

#define N_NODES 50000
#define N_EDGES 800000
#define EPS 1e-5f

typedef __attribute__((ext_vector_type(8))) short bf16x8;
typedef __attribute__((ext_vector_type(4))) float f32x4;
typedef __attribute__((ext_vector_type(4))) unsigned short us4;

__device__ __forceinline__ unsigned short f2b(float f) {
    union { float f; unsigned int u; } v; v.f = f;
    unsigned int r = v.u + 0x7fffu + ((v.u >> 16) & 1u);
    return (unsigned short)(r >> 16);
}
__device__ __forceinline__ float b2f(unsigned short b) {
    union { unsigned int u; float f; } v; v.u = ((unsigned int)b) << 16;
    return v.f;
}

// red layout per layer: 64 buckets * 16 floats (one 64B line per bucket).
#define RED_BUCKETS 64
#define RED_FLOATS_PER_LAYER (RED_BUCKETS * 16)

// ---------------- prep: init + f32->bf16 converts in one launch ----------------

#define CV_NX (N_NODES * 128 / 4)
#define CV_N0 (256 * 128 / 4)
#define CV_N1 (256 * 256 / 4)
#define CV_N2 (128 * 256 / 4)

__global__ void prep_kernel(const float* __restrict__ x0, const float* __restrict__ W0,
                            const float* __restrict__ W1, const float* __restrict__ W2,
                            unsigned short* __restrict__ xb, unsigned short* __restrict__ wb0,
                            unsigned short* __restrict__ wb1, unsigned short* __restrict__ wb2,
                            int* __restrict__ deg, int* __restrict__ fill,
                            float* __restrict__ red) {
    int i = blockIdx.x * 256 + threadIdx.x;
    if (i < N_NODES) { deg[i] = 0; fill[i] = 0; }
    if (i < 3 * RED_FLOATS_PER_LAYER) red[i] = 0.f;
    const float* s;
    unsigned short* d;
    int j = i;
    if (j < CV_NX) { s = x0; d = xb; }
    else if ((j -= CV_NX) < CV_N0) { s = W0; d = wb0; }
    else if ((j -= CV_N0) < CV_N1) { s = W1; d = wb1; }
    else if ((j -= CV_N1) < CV_N2) { s = W2; d = wb2; }
    else return;
    float4 v = reinterpret_cast<const float4*>(s)[j];
    us4 o;
    o[0] = f2b(v.x); o[1] = f2b(v.y); o[2] = f2b(v.z); o[3] = f2b(v.w);
    reinterpret_cast<us4*>(d)[j] = o;
}

// ---------------- CSR build ----------------

__global__ void count_kernel(const int* __restrict__ dst, int* __restrict__ deg, int e) {
    for (int i = blockIdx.x * blockDim.x + threadIdx.x; i < e; i += gridDim.x * blockDim.x)
        atomicAdd(&deg[dst[i]], 1);
}

__global__ void scan1_kernel(const int* __restrict__ deg, float* __restrict__ dinv,
                             int* __restrict__ bsum, int n) {
    int i = blockIdx.x * 256 + threadIdx.x;
    int v = (i < n) ? deg[i] : 0;
    if (i < n) dinv[i] = rsqrtf((float)(v + 1));  // +1 self-loop
    int t = v;
    #pragma unroll
    for (int off = 1; off < 64; off <<= 1) t += __shfl_xor(t, off);
    __shared__ int wsum[4];
    int wid = threadIdx.x >> 6, lane = threadIdx.x & 63;
    if (lane == 0) wsum[wid] = t;
    __syncthreads();
    if (threadIdx.x == 0) bsum[blockIdx.x] = wsum[0] + wsum[1] + wsum[2] + wsum[3];
}

__global__ void scan2_kernel(const int* __restrict__ bsum, int* __restrict__ bpre, int nb) {
    __shared__ int sm[256];
    int t = threadIdx.x;
    sm[t] = (t < nb) ? bsum[t] : 0;
    __syncthreads();
    #pragma unroll
    for (int d = 1; d < 256; d <<= 1) {
        int x = (t >= d) ? sm[t - d] : 0;
        __syncthreads();
        sm[t] += x;
        __syncthreads();
    }
    bpre[t] = (t > 0) ? sm[t - 1] : 0;  // exclusive
}

__global__ void scan3_kernel(const int* __restrict__ deg, const int* __restrict__ bpre,
                             int* __restrict__ off, int n) {
    __shared__ int sm[256];
    int t = threadIdx.x;
    int i = blockIdx.x * 256 + t;
    int v = (i < n) ? deg[i] : 0;
    sm[t] = v;
    __syncthreads();
    #pragma unroll
    for (int d = 1; d < 256; d <<= 1) {
        int x = (t >= d) ? sm[t - d] : 0;
        __syncthreads();
        sm[t] += x;
        __syncthreads();
    }
    if (i < n) off[i + 1] = sm[t] + bpre[blockIdx.x];
    if (i == 0) off[0] = 0;
}

// pack (src, bf16 weight) into one u32: src in low 16 bits (N_NODES < 65536)
__global__ void scatter_kernel(const int* __restrict__ src, const int* __restrict__ dst,
                               const int* __restrict__ coff, int* __restrict__ fill,
                               const float* __restrict__ dinv,
                               unsigned int* __restrict__ epack, int e) {
    for (int i = blockIdx.x * blockDim.x + threadIdx.x; i < e; i += gridDim.x * blockDim.x) {
        int d = dst[i];
        int s = src[i];
        int pos = coff[d] + atomicAdd(&fill[d], 1);
        epack[pos] = ((unsigned int)f2b(dinv[s] * dinv[d]) << 16) | (unsigned int)s;
    }
}

// ---------------- GEMM body ----------------
// C[m][n] = sum_k T(X[m][k]) * W[n][k] (+bias). BM=64, BN=fout, BK=32, 4 waves.
// W-frags direct from global (each wave owns a disjoint 64/32-col slice; W is L1/L2-hot).
// X staged in double-buffered LDS (shared across waves), transform applied at stage.
// MFMA operands SWAPPED (mfma(b,a)): lane holds 4 consecutive C-columns -> us4 stores.

template<int BN, bool TRANSFORM, bool ADD_BIAS, bool FUSE_RED>
__device__ __forceinline__ void gemm_body(
    const unsigned short* __restrict__ Xin, const unsigned short* __restrict__ Wb,
    const float* __restrict__ bias, const float* __restrict__ redin,
    const float* __restrict__ gw, const float* __restrict__ bw,
    const float* __restrict__ asl, float* __restrict__ redout,
    unsigned short* __restrict__ Hout, int M, int K, float inv_count) {
    constexpr int FR_N = BN / 64;
    __shared__ unsigned short xs[2][64 * 32];
    int tid = threadIdx.x;
    int wid = tid >> 6, lane = tid & 63;
    int l16 = lane & 15, kg = lane >> 4;
    int srow = tid >> 2, sblk = tid & 3;
    int m0 = blockIdx.x * 64;
    int colbase = wid * (BN / 4);

    float mu = 0.f, rstd = 0.f, alpha = 0.f;
    if (TRANSFORM) {
        float s = redin[lane * 16], s2 = redin[lane * 16 + 1];
        #pragma unroll
        for (int off = 1; off < 64; off <<= 1) { s += __shfl_xor(s, off); s2 += __shfl_xor(s2, off); }
        mu = s * inv_count;
        rstd = rsqrtf(s2 * inv_count - mu * mu + EPS);
        alpha = asl[0];
    }

    int gm = m0 + srow;
    bool inm = (gm < M);
    const unsigned short* xrow = Xin + (size_t)gm * K + sblk * 8;
    unsigned short* xdst = &xs[0][srow * 32 + ((sblk ^ (srow & 3)) * 8)];

    // stage one 64x32 X tile into buffer `buf` for k-offset k0
    auto stage = [&](int k0, int buf) {
        bf16x8 xv = {};
        if (inm) {
            bf16x8 u = *reinterpret_cast<const bf16x8*>(xrow + k0);
            if (TRANSFORM) {
                int f0 = k0 + sblk * 8;
                float ga[8], ba[8];
                *reinterpret_cast<float4*>(&ga[0]) = *reinterpret_cast<const float4*>(gw + f0);
                *reinterpret_cast<float4*>(&ga[4]) = *reinterpret_cast<const float4*>(gw + f0 + 4);
                *reinterpret_cast<float4*>(&ba[0]) = *reinterpret_cast<const float4*>(bw + f0);
                *reinterpret_cast<float4*>(&ba[4]) = *reinterpret_cast<const float4*>(bw + f0 + 4);
                #pragma unroll
                for (int i = 0; i < 8; ++i) {
                    float A = rstd * ga[i];
                    float B = ba[i] - mu * A;
                    float v = fmaf(b2f((unsigned short)u[i]), A, B);
                    v = fmaf(fminf(v, 0.f), alpha - 1.0f, v);  // v>=0: v ; v<0: alpha*v
                    xv[i] = (short)f2b(v);
                }
            } else {
                xv = u;
            }
        }
        *reinterpret_cast<bf16x8*>(xdst + buf * (64 * 32)) = xv;
    };

    stage(0, 0);
    f32x4 acc[4][FR_N] = {};
    int nsteps = K / 32;
    for (int s = 0; s < nsteps; ++s) {
        __syncthreads();
        int k0 = s * 32;
        if (s + 1 < nsteps) stage(k0 + 32, (s + 1) & 1);
        bf16x8 b[FR_N];
        #pragma unroll
        for (int j = 0; j < FR_N; ++j)
            b[j] = *reinterpret_cast<const bf16x8*>(
                Wb + (size_t)(colbase + j * 16 + l16) * K + k0 + kg * 8);
        const unsigned short* xbuf = xs[s & 1];
        bf16x8 a[4];
        #pragma unroll
        for (int i = 0; i < 4; ++i) {
            int ar = i * 16 + l16;
            a[i] = *reinterpret_cast<const bf16x8*>(xbuf + ar * 32 + ((kg ^ (ar & 3)) * 8));
        }
        #pragma unroll
        for (int i = 0; i < 4; ++i)
            #pragma unroll
            for (int j = 0; j < FR_N; ++j)
                acc[i][j] = __builtin_amdgcn_mfma_f32_16x16x32_bf16(b[j], a[i], acc[i][j], 0, 0, 0);
    }

    // epilogue: lane holds C[row=m0+i*16+l16][cols=colbase+j*16+kg*4 .. +3]
    float bsel[FR_N][4];
    if (ADD_BIAS) {
        #pragma unroll
        for (int j = 0; j < FR_N; ++j)
            *reinterpret_cast<float4*>(bsel[j]) =
                *reinterpret_cast<const float4*>(bias + colbase + j * 16 + kg * 4);
    }
    float s = 0.f, s2 = 0.f;
    #pragma unroll
    for (int i = 0; i < 4; ++i) {
        int row = m0 + i * 16 + l16;
        if (row < M) {
            #pragma unroll
            for (int j = 0; j < FR_N; ++j) {
                us4 o;
                #pragma unroll
                for (int r = 0; r < 4; ++r) {
                    float v = acc[i][j][r] + (ADD_BIAS ? bsel[j][r] : 0.f);
                    if (FUSE_RED) { s += v; s2 += v * v; }
                    o[r] = f2b(v);
                }
                *reinterpret_cast<us4*>(Hout + (size_t)row * BN + colbase + j * 16 + kg * 4) = o;
            }
        }
    }
    if (FUSE_RED) {
        #pragma unroll
        for (int off = 1; off < 64; off <<= 1) { s += __shfl_xor(s, off); s2 += __shfl_xor(s2, off); }
        if (lane == 0) {
            int bkt = (blockIdx.x & (RED_BUCKETS - 1)) * 16;
            atomicAdd(&redout[bkt], s);
            atomicAdd(&redout[bkt + 1], s2);
        }
    }
}

// ---------------- aggregation body: wave per node, depth-2 pipelined gather ----------------

template<int COLS, bool ADD_BIAS, bool FUSE_RED>
__device__ __forceinline__ void agg_body(
    const unsigned short* __restrict__ Hb, const int* __restrict__ coff,
    const unsigned int* __restrict__ epack, const float* __restrict__ dinv,
    const float* __restrict__ bias, unsigned short* __restrict__ Y,
    float* __restrict__ red) {
    constexpr int RL = COLS / 8;   // lanes per row (16B each): 16 or 32
    constexpr int NG = 64 / RL;    // neighbor groups per wave: 4 or 2
    int node = blockIdx.x * 4 + (threadIdx.x >> 6);
    int lane = threadIdx.x & 63;
    int g = lane / RL;
    int rl = lane % RL;
    float di = dinv[node];
    int s0 = coff[node], s1 = coff[node + 1];
    float acc[8] = {};

    int k = s0 - 1 + g;
    int sc; float wc;
    bf16x8 vc;
    bool have = (k < s1);
    if (have) {
        if (k < s0) { sc = node; wc = di * di; }
        else { unsigned int u = epack[k]; sc = u & 0xffff; wc = b2f((unsigned short)(u >> 16)); }
        vc = *reinterpret_cast<const bf16x8*>(Hb + (size_t)sc * COLS + rl * 8);
    }
    while (have) {
        int k2 = k + NG;
        bool have2 = (k2 < s1);
        int sn = 0; float wn = 0.f;
        bf16x8 vn;
        if (have2) {
            unsigned int u = epack[k2];
            sn = u & 0xffff; wn = b2f((unsigned short)(u >> 16));
            vn = *reinterpret_cast<const bf16x8*>(Hb + (size_t)sn * COLS + rl * 8);
        }
        #pragma unroll
        for (int i = 0; i < 8; ++i) acc[i] += wc * b2f((unsigned short)vc[i]);
        k = k2; wc = wn; vc = vn; have = have2;
    }

    #pragma unroll
    for (int off = RL; off < 64; off <<= 1) {
        #pragma unroll
        for (int i = 0; i < 8; ++i) acc[i] += __shfl_xor(acc[i], off);
    }
    if (ADD_BIAS) {
        #pragma unroll
        for (int i = 0; i < 8; ++i) acc[i] += bias[rl * 8 + i];
    }
    if (FUSE_RED) {
        float s = 0.f, s2 = 0.f;
        if (g == 0) {
            #pragma unroll
            for (int i = 0; i < 8; ++i) { s += acc[i]; s2 += acc[i] * acc[i]; }
        }
        #pragma unroll
        for (int off = 1; off < 64; off <<= 1) { s += __shfl_xor(s, off); s2 += __shfl_xor(s2, off); }
        if (lane == 0) {
            int bkt = (blockIdx.x & (RED_BUCKETS - 1)) * 16;
            atomicAdd(&red[bkt], s);
            atomicAdd(&red[bkt + 1], s2);
        }
    }
    if (g == 0) {
        bf16x8 o;
        #pragma unroll
        for (int i = 0; i < 8; ++i) o[i] = (short)f2b(acc[i]);
        __builtin_nontemporal_store(o, reinterpret_cast<bf16x8*>(Y + (size_t)node * COLS + rl * 8));
    }
}

// ---------------- distinctly-named wrappers (per-layer visibility in rocprof) ----------------

__global__ __launch_bounds__(256) void gemm_l0(const unsigned short* X, const unsigned short* W,
                                               const float* bias, float* redout,
                                               unsigned short* H, int M, int K, float ic) {
    gemm_body<256, false, true, true>(X, W, bias, nullptr, nullptr, nullptr, nullptr, redout, H, M, K, ic);
}
__global__ __launch_bounds__(256) void gemm_l1(const unsigned short* X, const unsigned short* W,
                                               const float* redin, const float* gw, const float* bw,
                                               const float* asl, unsigned short* H, int M, int K, float ic) {
    gemm_body<256, true, false, false>(X, W, nullptr, redin, gw, bw, asl, nullptr, H, M, K, ic);
}
__global__ __launch_bounds__(256) void gemm_l2(const unsigned short* X, const unsigned short* W,
                                               const float* redin, const float* gw, const float* bw,
                                               const float* asl, unsigned short* H, int M, int K, float ic) {
    gemm_body<128, true, false, false>(X, W, nullptr, redin, gw, bw, asl, nullptr, H, M, K, ic);
}
__global__ void agg_l0(const unsigned short* Hb, const int* coff, const unsigned int* ep,
                       const float* dinv, unsigned short* Y) {
    agg_body<128, false, false>(Hb, coff, ep, dinv, nullptr, Y, nullptr);
}
__global__ void agg_l1(const unsigned short* Hb, const int* coff, const unsigned int* ep,
                       const float* dinv, const float* bias, unsigned short* Y, float* red) {
    agg_body<256, true, true>(Hb, coff, ep, dinv, bias, Y, red);
}
__global__ void agg_l2(const unsigned short* Hb, const int* coff, const unsigned int* ep,
                       const float* dinv, const float* bias, unsigned short* Y, float* red) {
    agg_body<128, true, true>(Hb, coff, ep, dinv, bias, Y, red);
}

// ---------------- final LayerNorm + PReLU (bf16 in, f32 out) ----------------

__global__ void norm_final(const unsigned short* __restrict__ Yb, const float* __restrict__ red,
                           const float* __restrict__ g, const float* __restrict__ be,
                           const float* __restrict__ a, float* __restrict__ X,
                           int fmask8, int n8, float inv_count) {
    int lane = threadIdx.x & 63;
    float s = red[lane * 16], s2 = red[lane * 16 + 1];
    #pragma unroll
    for (int off = 1; off < 64; off <<= 1) { s += __shfl_xor(s, off); s2 += __shfl_xor(s2, off); }
    float mu = s * inv_count;
    float rstd = rsqrtf(s2 * inv_count - mu * mu + EPS);
    float alpha = a[0];
    for (int i = blockIdx.x * blockDim.x + threadIdx.x; i < n8; i += gridDim.x * blockDim.x) {
        bf16x8 v = reinterpret_cast<const bf16x8*>(Yb)[i];
        int fb = (i & fmask8) * 8;
        float o[8];
        #pragma unroll
        for (int j = 0; j < 8; ++j) {
            float t = (b2f((unsigned short)v[j]) - mu) * rstd * g[fb + j] + be[fb + j];
            o[j] = t >= 0.f ? t : alpha * t;
        }
        float* xp = X + (size_t)i * 8;
        *reinterpret_cast<float4*>(xp) = make_float4(o[0], o[1], o[2], o[3]);
        *reinterpret_cast<float4*>(xp + 4) = make_float4(o[4], o[5], o[6], o[7]);
    }
}

// ---------------- launch ----------------

extern "C" void kernel_launch(void* const* d_in, const int* in_sizes, int n_in,
                              void* d_out, int out_size, void* d_ws, size_t ws_size,
                              hipStream_t stream) {
    const float* x0 = (const float*)d_in[0];
    const int* ei = (const int*)d_in[1];
    const float* W[3] = {(const float*)d_in[2], (const float*)d_in[7], (const float*)d_in[12]};
    const float* bb[3] = {(const float*)d_in[3], (const float*)d_in[8], (const float*)d_in[13]};
    const float* gg[3] = {(const float*)d_in[4], (const float*)d_in[9], (const float*)d_in[14]};
    const float* be[3] = {(const float*)d_in[5], (const float*)d_in[10], (const float*)d_in[15]};
    const float* aa[3] = {(const float*)d_in[6], (const float*)d_in[11], (const float*)d_in[16]};

    char* ws = (char*)d_ws;
    size_t o = 0;
    auto alloc = [&](size_t bytes) {
        void* p = ws + o;
        o = (o + bytes + 255) & ~(size_t)255;
        return p;
    };
    int* deg = (int*)alloc(N_NODES * 4);
    int* fill = (int*)alloc(N_NODES * 4);
    int* coff = (int*)alloc((N_NODES + 1) * 4);
    unsigned int* epack = (unsigned int*)alloc((size_t)N_EDGES * 4);
    float* dinv = (float*)alloc(N_NODES * 4);
    int* bsum = (int*)alloc(256 * 4);
    int* bpre = (int*)alloc(256 * 4);
    float* red = (float*)alloc(3 * RED_FLOATS_PER_LAYER * 4);
    unsigned short* Wb0 = (unsigned short*)alloc(256 * 128 * 2);
    unsigned short* Wb1 = (unsigned short*)alloc(256 * 256 * 2);
    unsigned short* Wb2 = (unsigned short*)alloc(128 * 256 * 2);
    unsigned short* xb = (unsigned short*)alloc((size_t)N_NODES * 128 * 2);
    unsigned short* hb = (unsigned short*)alloc((size_t)N_NODES * 256 * 2);
    unsigned short* yb = (unsigned short*)alloc((size_t)N_NODES * 256 * 2);

    const int* e_src = ei;
    const int* e_dst = ei + N_EDGES;
    int nb = (N_NODES + 255) / 256;  // 196

    // prep (init + converts)
    int cvtot = CV_NX + CV_N0 + CV_N1 + CV_N2;
    prep_kernel<<<(cvtot + 255) / 256, 256, 0, stream>>>(x0, W[0], W[1], W[2], xb, Wb0, Wb1, Wb2,
                                                         deg, fill, red);
    // CSR build
    count_kernel<<<2048, 256, 0, stream>>>(e_dst, deg, N_EDGES);
    scan1_kernel<<<nb, 256, 0, stream>>>(deg, dinv, bsum, N_NODES);
    scan2_kernel<<<1, 256, 0, stream>>>(bsum, bpre, nb);
    scan3_kernel<<<nb, 256, 0, stream>>>(deg, bpre, coff, N_NODES);
    scatter_kernel<<<2048, 256, 0, stream>>>(e_src, e_dst, coff, fill, dinv, epack, N_EDGES);

    int gm = (N_NODES + 63) / 64;  // 782
    float ic256 = 1.0f / (N_NODES * 256.0f);
    float ic128 = 1.0f / (N_NODES * 128.0f);

    // ---- Layer 0 ----
    agg_l0<<<12500, 256, 0, stream>>>(xb, coff, epack, dinv, hb);
    gemm_l0<<<gm, 256, 0, stream>>>(hb, Wb0, bb[0], red + 0, yb, N_NODES, 128, ic256);

    // ---- Layer 1 ----
    gemm_l1<<<gm, 256, 0, stream>>>(yb, Wb1, red + 0, gg[0], be[0], aa[0], hb, N_NODES, 256, ic256);
    agg_l1<<<12500, 256, 0, stream>>>(hb, coff, epack, dinv, bb[1], yb, red + RED_FLOATS_PER_LAYER);

    // ---- Layer 2 ----
    gemm_l2<<<gm, 256, 0, stream>>>(yb, Wb2, red + RED_FLOATS_PER_LAYER, gg[1], be[1], aa[1], hb,
                                    N_NODES, 256, ic256);
    agg_l2<<<12500, 256, 0, stream>>>(hb, coff, epack, dinv, bb[2], yb,
                                      red + 2 * RED_FLOATS_PER_LAYER);

    // ---- final LN + PReLU -> d_out f32 ----
    norm_final<<<2048, 256, 0, stream>>>(yb, red + 2 * RED_FLOATS_PER_LAYER, gg[2], be[2], aa[2],
                                         (float*)d_out, 15, N_NODES * 128 / 8, ic128);
}

// Round 8
// 328.576 us; speedup vs baseline: 1.0384x; 1.0382x over previous
//
#include <hip/hip_runtime.h>

#define N_NODES 50000
#define N_EDGES 800000
#define EPS 1e-5f

typedef __attribute__((ext_vector_type(8))) short bf16x8;
typedef __attribute__((ext_vector_type(4))) float f32x4;
typedef __attribute__((ext_vector_type(4))) unsigned short us4;

__device__ __forceinline__ unsigned short f2b(float f) {
    union { float f; unsigned int u; } v; v.f = f;
    unsigned int r = v.u + 0x7fffu + ((v.u >> 16) & 1u);
    return (unsigned short)(r >> 16);
}
__device__ __forceinline__ float b2f(unsigned short b) {
    union { unsigned int u; float f; } v; v.u = ((unsigned int)b) << 16;
    return v.f;
}

// Feature matrices are CHUNK-MAJOR: elem(n,c) at ((c>>5)*N_NODES + n)*32 + (c&31).
// A 32-col chunk = contiguous 3.2MB region -> fits one XCD's 4MB L2 during gather.

#define RED_BUCKETS 64
#define RED_FLOATS_PER_LAYER (RED_BUCKETS * 16)

// ---------------- prep: init + f32->bf16 converts in one launch ----------------

#define CV_NX (N_NODES * 128 / 4)
#define CV_N0 (256 * 128 / 4)
#define CV_N1 (256 * 256 / 4)
#define CV_N2 (128 * 256 / 4)

__global__ void prep_kernel(const float* __restrict__ x0, const float* __restrict__ W0,
                            const float* __restrict__ W1, const float* __restrict__ W2,
                            unsigned short* __restrict__ xb, unsigned short* __restrict__ wb0,
                            unsigned short* __restrict__ wb1, unsigned short* __restrict__ wb2,
                            int* __restrict__ deg, int* __restrict__ fill,
                            float* __restrict__ red) {
    int i = blockIdx.x * 256 + threadIdx.x;
    if (i < N_NODES) { deg[i] = 0; fill[i] = 0; }
    if (i < 3 * RED_FLOATS_PER_LAYER) red[i] = 0.f;
    int j = i;
    if (j < CV_NX) {
        // x -> chunk-major xb. float4 j: node = j>>5, col0 = (j&31)*4
        float4 v = reinterpret_cast<const float4*>(x0)[j];
        int n = j >> 5;
        int col0 = (j & 31) * 4;
        us4 o;
        o[0] = f2b(v.x); o[1] = f2b(v.y); o[2] = f2b(v.z); o[3] = f2b(v.w);
        *reinterpret_cast<us4*>(xb + ((size_t)(col0 >> 5) * N_NODES + n) * 32 + (col0 & 31)) = o;
        return;
    }
    const float* s;
    unsigned short* d;
    if ((j -= CV_NX) < CV_N0) { s = W0; d = wb0; }
    else if ((j -= CV_N0) < CV_N1) { s = W1; d = wb1; }
    else if ((j -= CV_N1) < CV_N2) { s = W2; d = wb2; }
    else return;
    float4 v = reinterpret_cast<const float4*>(s)[j];
    us4 o;
    o[0] = f2b(v.x); o[1] = f2b(v.y); o[2] = f2b(v.z); o[3] = f2b(v.w);
    reinterpret_cast<us4*>(d)[j] = o;
}

// ---------------- CSR build ----------------

__global__ void count_kernel(const int* __restrict__ dst, int* __restrict__ deg, int e) {
    for (int i = blockIdx.x * blockDim.x + threadIdx.x; i < e; i += gridDim.x * blockDim.x)
        atomicAdd(&deg[dst[i]], 1);
}

__global__ void scan1_kernel(const int* __restrict__ deg, float* __restrict__ dinv,
                             int* __restrict__ bsum, int n) {
    int i = blockIdx.x * 256 + threadIdx.x;
    int v = (i < n) ? deg[i] : 0;
    if (i < n) dinv[i] = rsqrtf((float)(v + 1));  // +1 self-loop
    int t = v;
    #pragma unroll
    for (int off = 1; off < 64; off <<= 1) t += __shfl_xor(t, off);
    __shared__ int wsum[4];
    int wid = threadIdx.x >> 6, lane = threadIdx.x & 63;
    if (lane == 0) wsum[wid] = t;
    __syncthreads();
    if (threadIdx.x == 0) bsum[blockIdx.x] = wsum[0] + wsum[1] + wsum[2] + wsum[3];
}

__global__ void scan2_kernel(const int* __restrict__ bsum, int* __restrict__ bpre, int nb) {
    __shared__ int sm[256];
    int t = threadIdx.x;
    sm[t] = (t < nb) ? bsum[t] : 0;
    __syncthreads();
    #pragma unroll
    for (int d = 1; d < 256; d <<= 1) {
        int x = (t >= d) ? sm[t - d] : 0;
        __syncthreads();
        sm[t] += x;
        __syncthreads();
    }
    bpre[t] = (t > 0) ? sm[t - 1] : 0;  // exclusive
}

__global__ void scan3_kernel(const int* __restrict__ deg, const int* __restrict__ bpre,
                             int* __restrict__ off, int n) {
    __shared__ int sm[256];
    int t = threadIdx.x;
    int i = blockIdx.x * 256 + t;
    int v = (i < n) ? deg[i] : 0;
    sm[t] = v;
    __syncthreads();
    #pragma unroll
    for (int d = 1; d < 256; d <<= 1) {
        int x = (t >= d) ? sm[t - d] : 0;
        __syncthreads();
        sm[t] += x;
        __syncthreads();
    }
    if (i < n) off[i + 1] = sm[t] + bpre[blockIdx.x];
    if (i == 0) off[0] = 0;
}

// pack (src, bf16 weight) into one u32: src in low 16 bits (N_NODES < 65536)
__global__ void scatter_kernel(const int* __restrict__ src, const int* __restrict__ dst,
                               const int* __restrict__ coff, int* __restrict__ fill,
                               const float* __restrict__ dinv,
                               unsigned int* __restrict__ epack, int e) {
    for (int i = blockIdx.x * blockDim.x + threadIdx.x; i < e; i += gridDim.x * blockDim.x) {
        int d = dst[i];
        int s = src[i];
        int pos = coff[d] + atomicAdd(&fill[d], 1);
        epack[pos] = ((unsigned int)f2b(dinv[s] * dinv[d]) << 16) | (unsigned int)s;
    }
}

// ---------------- GEMM body (chunk-major X in, chunk-major H out) ----------------
// C[m][n] = sum_k T(X[m][k]) * W[n][k] (+bias). BM=64, BN=fout, BK=32, 4 waves.

template<int BN, bool TRANSFORM, bool ADD_BIAS, bool FUSE_RED>
__device__ __forceinline__ void gemm_body(
    const unsigned short* __restrict__ Xin, const unsigned short* __restrict__ Wb,
    const float* __restrict__ bias, const float* __restrict__ redin,
    const float* __restrict__ gw, const float* __restrict__ bw,
    const float* __restrict__ asl, float* __restrict__ redout,
    unsigned short* __restrict__ Hout, int M, int K, float inv_count) {
    constexpr int FR_N = BN / 64;
    __shared__ unsigned short xs[2][64 * 32];
    int tid = threadIdx.x;
    int wid = tid >> 6, lane = tid & 63;
    int l16 = lane & 15, kg = lane >> 4;
    int srow = tid >> 2, sblk = tid & 3;
    int m0 = blockIdx.x * 64;
    int colbase = wid * (BN / 4);

    float mu = 0.f, rstd = 0.f, alpha = 0.f;
    if (TRANSFORM) {
        float s = redin[lane * 16], s2 = redin[lane * 16 + 1];
        #pragma unroll
        for (int off = 1; off < 64; off <<= 1) { s += __shfl_xor(s, off); s2 += __shfl_xor(s2, off); }
        mu = s * inv_count;
        rstd = rsqrtf(s2 * inv_count - mu * mu + EPS);
        alpha = asl[0];
    }

    int gmr = m0 + srow;
    bool inm = (gmr < M);
    // chunk-major: 16B at (row, k0+sblk*8) = Xin + ((k0>>5)*N + row)*32 + sblk*8
    const unsigned short* xrow = Xin + (size_t)gmr * 32 + sblk * 8;
    unsigned short* xdst = &xs[0][srow * 32 + ((sblk ^ (srow & 3)) * 8)];

    auto stage = [&](int k0, int buf) {
        bf16x8 xv = {};
        if (inm) {
            bf16x8 u = *reinterpret_cast<const bf16x8*>(xrow + (size_t)(k0 >> 5) * N_NODES * 32);
            if (TRANSFORM) {
                int f0 = k0 + sblk * 8;
                float ga[8], ba[8];
                *reinterpret_cast<float4*>(&ga[0]) = *reinterpret_cast<const float4*>(gw + f0);
                *reinterpret_cast<float4*>(&ga[4]) = *reinterpret_cast<const float4*>(gw + f0 + 4);
                *reinterpret_cast<float4*>(&ba[0]) = *reinterpret_cast<const float4*>(bw + f0);
                *reinterpret_cast<float4*>(&ba[4]) = *reinterpret_cast<const float4*>(bw + f0 + 4);
                #pragma unroll
                for (int i = 0; i < 8; ++i) {
                    float A = rstd * ga[i];
                    float B = ba[i] - mu * A;
                    float v = fmaf(b2f((unsigned short)u[i]), A, B);
                    v = fmaf(fminf(v, 0.f), alpha - 1.0f, v);
                    xv[i] = (short)f2b(v);
                }
            } else {
                xv = u;
            }
        }
        *reinterpret_cast<bf16x8*>(xdst + buf * (64 * 32)) = xv;
    };

    stage(0, 0);
    f32x4 acc[4][FR_N] = {};
    int nsteps = K / 32;
    for (int s = 0; s < nsteps; ++s) {
        __syncthreads();
        int k0 = s * 32;
        if (s + 1 < nsteps) stage(k0 + 32, (s + 1) & 1);
        bf16x8 b[FR_N];
        #pragma unroll
        for (int j = 0; j < FR_N; ++j)
            b[j] = *reinterpret_cast<const bf16x8*>(
                Wb + (size_t)(colbase + j * 16 + l16) * K + k0 + kg * 8);
        const unsigned short* xbuf = xs[s & 1];
        bf16x8 a[4];
        #pragma unroll
        for (int i = 0; i < 4; ++i) {
            int ar = i * 16 + l16;
            a[i] = *reinterpret_cast<const bf16x8*>(xbuf + ar * 32 + ((kg ^ (ar & 3)) * 8));
        }
        #pragma unroll
        for (int i = 0; i < 4; ++i)
            #pragma unroll
            for (int j = 0; j < FR_N; ++j)
                acc[i][j] = __builtin_amdgcn_mfma_f32_16x16x32_bf16(b[j], a[i], acc[i][j], 0, 0, 0);
    }

    float bsel[FR_N][4];
    if (ADD_BIAS) {
        #pragma unroll
        for (int j = 0; j < FR_N; ++j)
            *reinterpret_cast<float4*>(bsel[j]) =
                *reinterpret_cast<const float4*>(bias + colbase + j * 16 + kg * 4);
    }
    float s = 0.f, s2 = 0.f;
    #pragma unroll
    for (int i = 0; i < 4; ++i) {
        int row = m0 + i * 16 + l16;
        if (row < M) {
            #pragma unroll
            for (int j = 0; j < FR_N; ++j) {
                int col = colbase + j * 16 + kg * 4;
                us4 o;
                #pragma unroll
                for (int r = 0; r < 4; ++r) {
                    float v = acc[i][j][r] + (ADD_BIAS ? bsel[j][r] : 0.f);
                    if (FUSE_RED) { s += v; s2 += v * v; }
                    o[r] = f2b(v);
                }
                *reinterpret_cast<us4*>(
                    Hout + ((size_t)(col >> 5) * N_NODES + row) * 32 + (col & 31)) = o;
            }
        }
    }
    if (FUSE_RED) {
        #pragma unroll
        for (int off = 1; off < 64; off <<= 1) { s += __shfl_xor(s, off); s2 += __shfl_xor(s2, off); }
        if (lane == 0) {
            int bkt = (blockIdx.x & (RED_BUCKETS - 1)) * 16;
            atomicAdd(&redout[bkt], s);
            atomicAdd(&redout[bkt + 1], s2);
        }
    }
}

// ---------------- aggregation: chunk-per-XCD, lane-private node accumulation ----------------
// Block = 64 nodes x one 32-col chunk; chunk = blockIdx % CHUNKS -> XCD affinity (round-robin
// dispatch), so each chunk's contiguous 3.2MB region stays in one XCD's L2.
// 4 lanes per node (16B each); each lane serially accumulates its node's neighbors.

template<int COLS, bool ADD_BIAS, bool FUSE_RED>
__device__ __forceinline__ void agg_body(
    const unsigned short* __restrict__ Hb, const int* __restrict__ coff,
    const unsigned int* __restrict__ epack, const float* __restrict__ dinv,
    const float* __restrict__ bias, unsigned short* __restrict__ Y,
    float* __restrict__ red) {
    constexpr int CHUNKS = COLS / 32;
    int chunk = blockIdx.x % CHUNKS;
    int nodeblk = blockIdx.x / CHUNKS;
    int t = threadIdx.x;
    int node = nodeblk * 64 + (t >> 2);
    int rl = t & 3;
    bool active = node < N_NODES;
    const unsigned short* base = Hb + (size_t)chunk * N_NODES * 32 + rl * 8;
    int s0 = 0, s1 = 0;
    float wc = 0.f;
    if (active) {
        s0 = coff[node]; s1 = coff[node + 1];
        float di = dinv[node];
        wc = di * di;
    }
    float acc[8] = {};
    int k = s0 - 1;            // slot -1 = self-loop
    bf16x8 vc = {};
    bool have = active;
    if (have) vc = *reinterpret_cast<const bf16x8*>(base + (size_t)node * 32);
    while (__any(have)) {
        int k2 = k + 1;
        bool have2 = have && (k2 < s1);
        float wn = 0.f;
        bf16x8 vn = {};
        if (have2) {
            unsigned int u = epack[k2];
            wn = b2f((unsigned short)(u >> 16));
            vn = *reinterpret_cast<const bf16x8*>(base + (size_t)(u & 0xffffu) * 32);
        }
        if (have) {
            #pragma unroll
            for (int i = 0; i < 8; ++i) acc[i] += wc * b2f((unsigned short)vc[i]);
        }
        k = k2; wc = wn; vc = vn; have = have2;
    }
    if (ADD_BIAS && active) {
        #pragma unroll
        for (int i = 0; i < 8; ++i) acc[i] += bias[chunk * 32 + rl * 8 + i];
    }
    if (FUSE_RED) {
        float s = 0.f, s2 = 0.f;
        #pragma unroll
        for (int i = 0; i < 8; ++i) { s += acc[i]; s2 += acc[i] * acc[i]; }
        #pragma unroll
        for (int off = 1; off < 64; off <<= 1) { s += __shfl_xor(s, off); s2 += __shfl_xor(s2, off); }
        if ((t & 63) == 0) {
            int bkt = (blockIdx.x & (RED_BUCKETS - 1)) * 16;
            atomicAdd(&red[bkt], s);
            atomicAdd(&red[bkt + 1], s2);
        }
    }
    if (active) {
        bf16x8 o;
        #pragma unroll
        for (int i = 0; i < 8; ++i) o[i] = (short)f2b(acc[i]);
        __builtin_nontemporal_store(
            o, reinterpret_cast<bf16x8*>(Y + ((size_t)chunk * N_NODES + node) * 32 + rl * 8));
    }
}

// ---------------- distinctly-named wrappers ----------------

__global__ __launch_bounds__(256) void gemm_l0(const unsigned short* X, const unsigned short* W,
                                               const float* bias, float* redout,
                                               unsigned short* H, int M, int K, float ic) {
    gemm_body<256, false, true, true>(X, W, bias, nullptr, nullptr, nullptr, nullptr, redout, H, M, K, ic);
}
__global__ __launch_bounds__(256) void gemm_l1(const unsigned short* X, const unsigned short* W,
                                               const float* redin, const float* gw, const float* bw,
                                               const float* asl, unsigned short* H, int M, int K, float ic) {
    gemm_body<256, true, false, false>(X, W, nullptr, redin, gw, bw, asl, nullptr, H, M, K, ic);
}
__global__ __launch_bounds__(256) void gemm_l2(const unsigned short* X, const unsigned short* W,
                                               const float* redin, const float* gw, const float* bw,
                                               const float* asl, unsigned short* H, int M, int K, float ic) {
    gemm_body<128, true, false, false>(X, W, nullptr, redin, gw, bw, asl, nullptr, H, M, K, ic);
}
__global__ void agg_l0(const unsigned short* Hb, const int* coff, const unsigned int* ep,
                       const float* dinv, unsigned short* Y) {
    agg_body<128, false, false>(Hb, coff, ep, dinv, nullptr, Y, nullptr);
}
__global__ void agg_l1(const unsigned short* Hb, const int* coff, const unsigned int* ep,
                       const float* dinv, const float* bias, unsigned short* Y, float* red) {
    agg_body<256, true, true>(Hb, coff, ep, dinv, bias, Y, red);
}
__global__ void agg_l2(const unsigned short* Hb, const int* coff, const unsigned int* ep,
                       const float* dinv, const float* bias, unsigned short* Y, float* red) {
    agg_body<128, true, true>(Hb, coff, ep, dinv, bias, Y, red);
}

// ---------------- final LayerNorm + PReLU (chunk-major bf16 in, standard f32 out) ----------------

__global__ void norm_final(const unsigned short* __restrict__ Yb, const float* __restrict__ red,
                           const float* __restrict__ g, const float* __restrict__ be,
                           const float* __restrict__ a, float* __restrict__ X,
                           float inv_count) {
    int lane = threadIdx.x & 63;
    float s = red[lane * 16], s2 = red[lane * 16 + 1];
    #pragma unroll
    for (int off = 1; off < 64; off <<= 1) { s += __shfl_xor(s, off); s2 += __shfl_xor(s2, off); }
    float mu = s * inv_count;
    float rstd = rsqrtf(s2 * inv_count - mu * mu + EPS);
    float alpha = a[0];
    int total = N_NODES * 128 / 8;
    for (int i = blockIdx.x * blockDim.x + threadIdx.x; i < total; i += gridDim.x * blockDim.x) {
        bf16x8 v = reinterpret_cast<const bf16x8*>(Yb)[i];
        int c = i / (N_NODES * 4);
        int rem = i - c * (N_NODES * 4);
        int n = rem >> 2;
        int r = rem & 3;
        int f0 = c * 32 + r * 8;
        float o[8];
        #pragma unroll
        for (int j = 0; j < 8; ++j) {
            float t = (b2f((unsigned short)v[j]) - mu) * rstd * g[f0 + j] + be[f0 + j];
            o[j] = t >= 0.f ? t : alpha * t;
        }
        float* xp = X + (size_t)n * 128 + f0;
        *reinterpret_cast<float4*>(xp) = make_float4(o[0], o[1], o[2], o[3]);
        *reinterpret_cast<float4*>(xp + 4) = make_float4(o[4], o[5], o[6], o[7]);
    }
}

// ---------------- launch ----------------

extern "C" void kernel_launch(void* const* d_in, const int* in_sizes, int n_in,
                              void* d_out, int out_size, void* d_ws, size_t ws_size,
                              hipStream_t stream) {
    const float* x0 = (const float*)d_in[0];
    const int* ei = (const int*)d_in[1];
    const float* W[3] = {(const float*)d_in[2], (const float*)d_in[7], (const float*)d_in[12]};
    const float* bb[3] = {(const float*)d_in[3], (const float*)d_in[8], (const float*)d_in[13]};
    const float* gg[3] = {(const float*)d_in[4], (const float*)d_in[9], (const float*)d_in[14]};
    const float* be[3] = {(const float*)d_in[5], (const float*)d_in[10], (const float*)d_in[15]};
    const float* aa[3] = {(const float*)d_in[6], (const float*)d_in[11], (const float*)d_in[16]};

    char* ws = (char*)d_ws;
    size_t o = 0;
    auto alloc = [&](size_t bytes) {
        void* p = ws + o;
        o = (o + bytes + 255) & ~(size_t)255;
        return p;
    };
    int* deg = (int*)alloc(N_NODES * 4);
    int* fill = (int*)alloc(N_NODES * 4);
    int* coff = (int*)alloc((N_NODES + 1) * 4);
    unsigned int* epack = (unsigned int*)alloc((size_t)N_EDGES * 4);
    float* dinv = (float*)alloc(N_NODES * 4);
    int* bsum = (int*)alloc(256 * 4);
    int* bpre = (int*)alloc(256 * 4);
    float* red = (float*)alloc(3 * RED_FLOATS_PER_LAYER * 4);
    unsigned short* Wb0 = (unsigned short*)alloc(256 * 128 * 2);
    unsigned short* Wb1 = (unsigned short*)alloc(256 * 256 * 2);
    unsigned short* Wb2 = (unsigned short*)alloc(128 * 256 * 2);
    unsigned short* xb = (unsigned short*)alloc((size_t)N_NODES * 128 * 2);
    unsigned short* hb = (unsigned short*)alloc((size_t)N_NODES * 256 * 2);
    unsigned short* yb = (unsigned short*)alloc((size_t)N_NODES * 256 * 2);

    const int* e_src = ei;
    const int* e_dst = ei + N_EDGES;
    int nb = (N_NODES + 255) / 256;  // 196

    int cvtot = CV_NX + CV_N0 + CV_N1 + CV_N2;
    prep_kernel<<<(cvtot + 255) / 256, 256, 0, stream>>>(x0, W[0], W[1], W[2], xb, Wb0, Wb1, Wb2,
                                                         deg, fill, red);
    count_kernel<<<2048, 256, 0, stream>>>(e_dst, deg, N_EDGES);
    scan1_kernel<<<nb, 256, 0, stream>>>(deg, dinv, bsum, N_NODES);
    scan2_kernel<<<1, 256, 0, stream>>>(bsum, bpre, nb);
    scan3_kernel<<<nb, 256, 0, stream>>>(deg, bpre, coff, N_NODES);
    scatter_kernel<<<2048, 256, 0, stream>>>(e_src, e_dst, coff, fill, dinv, epack, N_EDGES);

    int gm = (N_NODES + 63) / 64;  // 782
    float ic256 = 1.0f / (N_NODES * 256.0f);
    float ic128 = 1.0f / (N_NODES * 128.0f);

    // ---- Layer 0 ----
    agg_l0<<<gm * 4, 256, 0, stream>>>(xb, coff, epack, dinv, hb);
    gemm_l0<<<gm, 256, 0, stream>>>(hb, Wb0, bb[0], red + 0, yb, N_NODES, 128, ic256);

    // ---- Layer 1 ----
    gemm_l1<<<gm, 256, 0, stream>>>(yb, Wb1, red + 0, gg[0], be[0], aa[0], hb, N_NODES, 256, ic256);
    agg_l1<<<gm * 8, 256, 0, stream>>>(hb, coff, epack, dinv, bb[1], yb, red + RED_FLOATS_PER_LAYER);

    // ---- Layer 2 ----
    gemm_l2<<<gm, 256, 0, stream>>>(yb, Wb2, red + RED_FLOATS_PER_LAYER, gg[1], be[1], aa[1], hb,
                                    N_NODES, 256, ic256);
    agg_l2<<<gm * 4, 256, 0, stream>>>(hb, coff, epack, dinv, bb[2], yb,
                                       red + 2 * RED_FLOATS_PER_LAYER);

    // ---- final LN + PReLU -> d_out f32 ----
    norm_final<<<2048, 256, 0, stream>>>(yb, red + 2 * RED_FLOATS_PER_LAYER, gg[2], be[2], aa[2],
                                         (float*)d_out, ic128);
}